// Round 3
// baseline (527.562 us; speedup 1.0000x reference)
//
#include <hip/hip_runtime.h>

typedef float  f32x4  __attribute__((ext_vector_type(4)));
typedef short  bf16x8 __attribute__((ext_vector_type(8)));
typedef short  s16x4  __attribute__((ext_vector_type(4)));

__device__ __forceinline__ unsigned short f2bf(float f) {
    unsigned int u = __float_as_uint(f);
    unsigned int r = (u + 0x7FFFu + ((u >> 16) & 1u)) >> 16;
    return (unsigned short)r;
}
__device__ __forceinline__ float bf2f(unsigned short h) {
    return __uint_as_float(((unsigned int)h) << 16);
}

// ---------------------------------------------------------------------------
// K0: t-means of x, non-atomic. grid (tc2=2, n=32, p=2), 256 thr.
// thread (c=tid>>2, q4=tid&3) accumulates 32 t-rows; shfl-reduce over q4.
// xmp layout: [tc2][p][n][c][v] fp32 (2 partial chunks, summed in k2).
// ---------------------------------------------------------------------------
__global__ __launch_bounds__(256) void k0_means(
    const float* __restrict__ x1, const float* __restrict__ x2,
    float* __restrict__ xmp)
{
    const int tc2 = blockIdx.x, n = blockIdx.y, p = blockIdx.z;
    const float* __restrict__ x = p ? x2 : x1;
    const int tid = threadIdx.x;
    const int c = tid >> 2, q4 = tid & 3;
    const float* base = x + (size_t)n * 409600 + (size_t)c * 6400
                      + (size_t)(tc2 * 128 + q4 * 32) * 25;
    f32x4 av[6];
    #pragma unroll
    for (int k = 0; k < 6; k++) av[k] = (f32x4){0.f, 0.f, 0.f, 0.f};
    float a24 = 0.f;
    #pragma unroll 4
    for (int r = 0; r < 32; r++) {
        const float* row = base + r * 25;
        #pragma unroll
        for (int k = 0; k < 6; k++) av[k] += *(const f32x4*)(row + 4 * k);
        a24 += row[24];
    }
    #pragma unroll
    for (int k = 0; k < 6; k++) {
        #pragma unroll
        for (int j = 0; j < 4; j++) {
            av[k][j] += __shfl_xor(av[k][j], 1, 64);
            av[k][j] += __shfl_xor(av[k][j], 2, 64);
        }
    }
    a24 += __shfl_xor(a24, 1, 64);
    a24 += __shfl_xor(a24, 2, 64);
    if (q4 == 0) {
        float* o = xmp + (size_t)tc2 * 102400
                 + ((size_t)(p * 32 + n) * 64 + c) * 25;
        #pragma unroll
        for (int k = 0; k < 6; k++)
            *(f32x4*)(o + 4 * k) = av[k] * (1.0f / 256.0f);
        o[24] = a24 * (1.0f / 256.0f);
    }
}

// ---------------------------------------------------------------------------
// K0B: pre-pack conv3/conv4 weights into MFMA A-fragment bf16 layout.
// awW: [p*3+i][w(4)][lane(64)][16 u16]  (af0 | af1)
// ---------------------------------------------------------------------------
__global__ void k0b_pack(const float* __restrict__ c3w, const float* __restrict__ c4w,
                         unsigned short* __restrict__ awW)
{
    const int pi = blockIdx.x;           // p*3+i
    const int p = pi / 3, i = pi % 3;
    const int tid = threadIdx.x;
    const int w = tid >> 6, lane = tid & 63, q = lane >> 4, m = lane & 15;
    const float* w3 = p ? c4w : c3w;
    const float* wr = w3 + (size_t)(i * 64 + w * 16 + m) * 64 + q * 8;
    const f32x4 w00 = *(const f32x4*)(wr);
    const f32x4 w01 = *(const f32x4*)(wr + 4);
    const f32x4 w10 = *(const f32x4*)(wr + 32);
    const f32x4 w11 = *(const f32x4*)(wr + 36);
    bf16x8 af0, af1;
    #pragma unroll
    for (int k = 0; k < 4; k++) {
        af0[k] = (short)f2bf(w00[k]); af0[k + 4] = (short)f2bf(w01[k]);
        af1[k] = (short)f2bf(w10[k]); af1[k + 4] = (short)f2bf(w11[k]);
    }
    unsigned short* o = awW + ((size_t)(pi * 4 + w) * 64 + lane) * 16;
    *(bf16x8*)(o)     = af0;
    *(bf16x8*)(o + 8) = af1;
}

// ---------------------------------------------------------------------------
// KA: x-transpose (2-stage LDS) + conv1x1 via MFMA. 64-pos tiles, all valid.
// grid (tc=100, n=32, p=2), 256 thr, LDS 25.6 KiB -> 6 blocks/CU.
// Writes X3 rows [ (p*32+n)*64 + c ][ tc*64 + pos ] bf16 into dst0/dst1.
// ---------------------------------------------------------------------------
__global__ __launch_bounds__(256, 6) void kA_conv(
    const float* __restrict__ x1, const float* __restrict__ x2,
    const float* __restrict__ c3b, const float* __restrict__ c4b,
    const unsigned short* __restrict__ awW,
    unsigned short* __restrict__ dst0, unsigned short* __restrict__ dst1,
    int ibase, int ni)
{
    const int tc = blockIdx.x, n = blockIdx.y, p = blockIdx.z;
    const float* __restrict__ x = p ? x2 : x1;
    __shared__ float tile1[64 * 68];             // fp32 [c][pos64 pad 68]
    __shared__ unsigned short tile2[64 * 64];    // bf16 [pos][c swizzled]
    const int tid = threadIdx.x;

    {   // pass 1: coalesced fp32 load of x[c][tc*64 .. +64)
        const size_t xb = (size_t)n * 409600 + (size_t)tc * 64;
        #pragma unroll
        for (int k = 0; k < 4; k++) {
            const int idx = tid + k * 256;
            const int c = idx >> 4, pg = idx & 15;
            *(f32x4*)(tile1 + c * 68 + pg * 4) =
                *(const f32x4*)(x + xb + (size_t)c * 6400 + pg * 4);
        }
    }
    __syncthreads();

    // pass 2: transpose to channel-last bf16, 8-channel-group XOR swizzle
    #pragma unroll
    for (int k = 0; k < 4; k++) {
        const int idx = tid + k * 256;
        const int pos = idx & 63, cq = idx >> 6;
        const float a0 = tile1[(cq * 4 + 0) * 68 + pos];
        const float a1 = tile1[(cq * 4 + 1) * 68 + pos];
        const float a2 = tile1[(cq * 4 + 2) * 68 + pos];
        const float a3 = tile1[(cq * 4 + 3) * 68 + pos];
        const unsigned long long pk =
            (unsigned long long)f2bf(a0)
          | ((unsigned long long)f2bf(a1) << 16)
          | ((unsigned long long)f2bf(a2) << 32)
          | ((unsigned long long)f2bf(a3) << 48);
        const int slot = (cq >> 1) ^ (pos & 7);
        *(unsigned long long*)(tile2 + pos * 64 + slot * 8 + (cq & 1) * 4) = pk;
    }
    __syncthreads();

    const int w = tid >> 6, lane = tid & 63, q = lane >> 4, m = lane & 15;
    const float* __restrict__ b3 = p ? c4b : c3b;

    for (int ii = 0; ii < ni; ii++) {
        const int i = ibase + ii;
        unsigned short* dst = ii ? dst1 : dst0;
        const unsigned short* wp =
            awW + ((size_t)((p * 3 + i) * 4 + w) * 64 + lane) * 16;
        const bf16x8 af0 = *(const bf16x8*)(wp);
        const bf16x8 af1 = *(const bf16x8*)(wp + 8);
        float bb[4];
        #pragma unroll
        for (int r = 0; r < 4; r++) bb[r] = b3[i * 64 + w * 16 + q * 4 + r];
        const size_t rb = ((size_t)(p * 32 + n) * 64 + w * 16 + q * 4) * 6400
                        + (size_t)tc * 64;
        #pragma unroll
        for (int nt = 0; nt < 4; nt++) {
            const int pos = nt * 16 + m;
            const int slot0 = q ^ (pos & 7);
            const bf16x8 xb0 = *(const bf16x8*)(tile2 + pos * 64 + slot0 * 8);
            const bf16x8 xb1 = *(const bf16x8*)(tile2 + pos * 64 + (slot0 ^ 4) * 8);
            f32x4 d = (f32x4){0.f, 0.f, 0.f, 0.f};
            d = __builtin_amdgcn_mfma_f32_16x16x32_bf16(af0, xb0, d, 0, 0, 0);
            d = __builtin_amdgcn_mfma_f32_16x16x32_bf16(af1, xb1, d, 0, 0, 0);
            #pragma unroll
            for (int r = 0; r < 4; r++)
                dst[rb + (size_t)r * 6400 + pos] = f2bf(d[r] + bb[r]);
        }
    }
}

// ---------------------------------------------------------------------------
// K2: r1/r2 -> rel -> a packed as MFMA B-fragments (bf16, zero-padded)
// grid: 192 blocks (i, n, p), 256 threads
// ---------------------------------------------------------------------------
__global__ void k2_adj(const float* __restrict__ xmp,
                       const float* __restrict__ PA, const float* __restrict__ alpha,
                       const float* __restrict__ c1w, const float* __restrict__ c1b,
                       const float* __restrict__ c2w, const float* __restrict__ c2b,
                       const float* __restrict__ c5w, const float* __restrict__ c5b,
                       const float* __restrict__ c6w, const float* __restrict__ c6b,
                       unsigned short* __restrict__ aw)
{
    const int b = blockIdx.x;
    const int i = b >> 6;
    const int n = (b >> 1) & 31;
    const int pp = b & 1;
    __shared__ float xml[3200];
    __shared__ float rl[400];
    __shared__ float rel[5000];
    const int tid = threadIdx.x;

    for (int idx = tid; idx < 3200; idx += 256) {
        const int p_ = idx / 1600, rest = idx % 1600;
        const size_t o = (size_t)(p_ * 32 + n) * 1600 + rest;
        xml[idx] = xmp[o] + xmp[102400 + o];
    }
    __syncthreads();

    for (int idx = tid; idx < 400; idx += 256) {
        const int which = idx / 200;
        const int rr = (idx % 200) / 25;
        const int v = idx % 25;
        const float* wv = (which ? c2w : c1w) + (i * 8 + rr) * 64;
        const float* xp = xml + which * 1600;
        float s = (which ? c2b : c1b)[i * 8 + rr];
        for (int c = 0; c < 64; c++) s += wv[c] * xp[c * 25 + v];
        rl[idx] = s;
    }
    __syncthreads();

    for (int idx = tid; idx < 5000; idx += 256) {
        const int r_ = idx / 625;
        const int rem = idx - r_ * 625;
        const int u = rem / 25;
        const int v = rem - u * 25;
        rel[idx] = tanhf(rl[r_ * 25 + u] - rl[200 + r_ * 25 + v]);
    }
    __syncthreads();

    const float al = alpha[0];
    {
        const int p_ = pp;
        const float* w5 = p_ ? c6w : c5w;
        const float* b5 = p_ ? c6b : c5b;
        for (int idx = tid; idx < 8192; idx += 256) {
            const int c = idx >> 7;
            const int ut = (idx >> 6) & 1;
            const int lane = idx & 63;
            const int u = ut * 16 + (lane & 15);
            const int qd = lane >> 4;
            bf16x8 outv;
            if (u < 25) {
                float wrow[8];
                #pragma unroll
                for (int r = 0; r < 8; r++) wrow[r] = w5[(i * 64 + c) * 8 + r];
                const float bias = b5[i * 64 + c];
                #pragma unroll
                for (int j = 0; j < 8; j++) {
                    const int v = qd * 8 + j;
                    float s = 0.f;
                    if (v < 25) {
                        s = bias + (p_ ? al : PA[i * 625 + u * 25 + v]);
                        #pragma unroll
                        for (int r = 0; r < 8; r++) s += rel[r * 625 + u * 25 + v] * wrow[r];
                    }
                    outv[j] = (short)f2bf(s);
                }
            } else {
                #pragma unroll
                for (int j = 0; j < 8; j++) outv[j] = 0;
            }
            *(bf16x8*)(aw + ((size_t)((p_ * 3 + i) * 32 + n) * 64 + c) * 1024
                          + ut * 512 + lane * 8) = outv;
        }
    }
}

// ---------------------------------------------------------------------------
// K3BA: z = X3_0 * a0 + X3_1 * a1, z ALIASED over buf0's own rows.
// grid: 4096 blocks (p, n, cg, tg): wave = channel cg*4+w, tiles tg*4..+4.
// ---------------------------------------------------------------------------
__global__ __launch_bounds__(256, 8) void k3bA(
    const unsigned short* __restrict__ aw,
    unsigned short* zb,                       // buf0: A(i=0) source + z dest
    const unsigned short* __restrict__ bufB)  // buf1: A(i=1)
{
    const int b = blockIdx.x;
    const int tg = b & 3;
    const int cg = (b >> 2) & 15;
    const int n  = (b >> 6) & 31;
    const int p  = b >> 11;
    const int tid = threadIdx.x;
    const int w = tid >> 6, lane = tid & 63, q = lane >> 4, m = lane & 15;
    const int c = cg * 4 + w;

    const size_t row = ((size_t)(p * 32 + n) * 64 + c) * 6400;
    const int aoff = m * 25 + q * 8;

    bf16x8 BA0, BA1, BB0, BB1;
    {
        const size_t a0 = ((size_t)((p * 3 + 0) * 32 + n) * 64 + c) * 1024 + lane * 8;
        const size_t a1 = ((size_t)((p * 3 + 1) * 32 + n) * 64 + c) * 1024 + lane * 8;
        BA0 = *(const bf16x8*)(aw + a0);
        BA1 = *(const bf16x8*)(aw + a0 + 512);
        BB0 = *(const bf16x8*)(aw + a1);
        BB1 = *(const bf16x8*)(aw + a1 + 512);
    }
    unsigned short* zr = zb + row;
    const unsigned short* pA = zb + row + (size_t)tg * 1600 + aoff;
    const unsigned short* pB = bufB + row + (size_t)tg * 1600 + aoff;

    bf16x8 A0 = *(const bf16x8*)(pA);
    bf16x8 A1 = *(const bf16x8*)(pB);
    for (int lt = 0; lt < 4; lt++) {
        bf16x8 nA0 = A0, nA1 = A1;
        if (lt < 3) {
            nA0 = *(const bf16x8*)(pA + (lt + 1) * 400);
            nA1 = *(const bf16x8*)(pB + (lt + 1) * 400);
        }
        f32x4 u0 = (f32x4){0.f,0.f,0.f,0.f}, u1 = (f32x4){0.f,0.f,0.f,0.f};
        u0 = __builtin_amdgcn_mfma_f32_16x16x32_bf16(A0, BA0, u0, 0, 0, 0);
        u0 = __builtin_amdgcn_mfma_f32_16x16x32_bf16(A1, BB0, u0, 0, 0, 0);
        u1 = __builtin_amdgcn_mfma_f32_16x16x32_bf16(A0, BA1, u1, 0, 0, 0);
        u1 = __builtin_amdgcn_mfma_f32_16x16x32_bf16(A1, BB1, u1, 0, 0, 0);
        #pragma unroll
        for (int r = 0; r < 4; r++) {
            const int o = (tg * 4 + lt) * 400 + (q * 4 + r) * 25;
            zr[o + m] = f2bf(u0[r]);
            if (m < 9) zr[o + 16 + m] = f2bf(u1[r]);
        }
        A0 = nA0; A1 = nA1;
    }
}

// ---------------------------------------------------------------------------
// K3BB: z += X3_2 * a2 (bf16 RMW) + BN sum/sumsq stats. Same grid as K3BA.
// ---------------------------------------------------------------------------
__global__ __launch_bounds__(256, 8) void k3bB(
    const unsigned short* __restrict__ aw,
    unsigned short* zb,                       // buf0: z RMW
    const unsigned short* __restrict__ bufB,  // buf1: A(i=2)
    float* __restrict__ stats)
{
    const int b = blockIdx.x;
    const int tg = b & 3;
    const int cg = (b >> 2) & 15;
    const int n  = (b >> 6) & 31;
    const int p  = b >> 11;
    const int tid = threadIdx.x;
    const int w = tid >> 6, lane = tid & 63, q = lane >> 4, m = lane & 15;
    const int c = cg * 4 + w;

    const size_t row = ((size_t)(p * 32 + n) * 64 + c) * 6400;
    const int aoff = m * 25 + q * 8;

    bf16x8 B0, B1;
    {
        const size_t a2 = ((size_t)((p * 3 + 2) * 32 + n) * 64 + c) * 1024 + lane * 8;
        B0 = *(const bf16x8*)(aw + a2);
        B1 = *(const bf16x8*)(aw + a2 + 512);
    }
    unsigned short* zr = zb + row;
    const unsigned short* pB = bufB + row + (size_t)tg * 1600 + aoff;

    float sum = 0.f, ssq = 0.f;
    bf16x8 A2 = *(const bf16x8*)(pB);
    for (int lt = 0; lt < 4; lt++) {
        bf16x8 nA2 = A2;
        if (lt < 3) nA2 = *(const bf16x8*)(pB + (lt + 1) * 400);
        f32x4 u0 = (f32x4){0.f,0.f,0.f,0.f}, u1 = (f32x4){0.f,0.f,0.f,0.f};
        u0 = __builtin_amdgcn_mfma_f32_16x16x32_bf16(A2, B0, u0, 0, 0, 0);
        u1 = __builtin_amdgcn_mfma_f32_16x16x32_bf16(A2, B1, u1, 0, 0, 0);
        #pragma unroll
        for (int r = 0; r < 4; r++) {
            const int o = (tg * 4 + lt) * 400 + (q * 4 + r) * 25;
            const float v0 = u0[r] + bf2f(zr[o + m]);
            zr[o + m] = f2bf(v0); sum += v0; ssq += v0 * v0;
            if (m < 9) {
                const float v1 = u1[r] + bf2f(zr[o + 16 + m]);
                zr[o + 16 + m] = f2bf(v1); sum += v1; ssq += v1 * v1;
            }
        }
        A2 = nA2;
    }
    #pragma unroll
    for (int off = 32; off > 0; off >>= 1) {
        sum += __shfl_xor(sum, off, 64);
        ssq += __shfl_xor(ssq, off, 64);
    }
    if (lane == 0) {
        atomicAdd(&stats[(p * 64 + c) * 2 + 0], sum);
        atomicAdd(&stats[(p * 64 + c) * 2 + 1], ssq);
    }
}

// ---------------------------------------------------------------------------
// K4: BN stats -> per-channel scale/shift
// ---------------------------------------------------------------------------
__global__ void k4_finalize(const float* __restrict__ stats,
                            const float* __restrict__ bn1w, const float* __restrict__ bn1b,
                            const float* __restrict__ bn2w, const float* __restrict__ bn2b,
                            float* __restrict__ ss)
{
    const int tid = threadIdx.x;
    if (tid < 128) {
        const int p = tid >> 6, c = tid & 63;
        const float cnt = 204800.f;   // N*T*V
        const float mean = stats[tid * 2] / cnt;
        const float var  = stats[tid * 2 + 1] / cnt - mean * mean;
        const float gw = p ? bn2w[c] : bn1w[c];
        const float gb = p ? bn2b[c] : bn1b[c];
        const float scale = gw * rsqrtf(var + 1e-5f);
        ss[tid * 2]     = scale;
        ss[tid * 2 + 1] = gb - mean * scale;
    }
}

// ---------------------------------------------------------------------------
// K5: y = relu(z*scale + shift + x), float4-wide  (z = buf0, same geometry)
// ---------------------------------------------------------------------------
__global__ void k5_apply(const float* __restrict__ x1, const float* __restrict__ x2,
                         const unsigned short* __restrict__ z, const float* __restrict__ ss,
                         float* __restrict__ out)
{
    const size_t g = (size_t)blockIdx.x * 256 + threadIdx.x;
    const size_t e = g * 4;
    const int p = (int)(e / 13107200u);
    const int c = (int)((e / 6400u) & 63);
    const float* xsrc = p ? x2 : x1;
    const f32x4 xv = *(const f32x4*)(xsrc + (e - (size_t)p * 13107200u));
    const s16x4 zv = *(const s16x4*)(const void*)(z + e);
    const float scale = ss[(p * 64 + c) * 2];
    const float shift = ss[(p * 64 + c) * 2 + 1];
    f32x4 o;
    #pragma unroll
    for (int k = 0; k < 4; k++) {
        const float zf = bf2f((unsigned short)zv[k]);
        const float y = zf * scale + shift + xv[k];
        o[k] = y > 0.f ? y : 0.f;
    }
    *(f32x4*)(out + e) = o;
}

// ---------------------------------------------------------------------------
extern "C" void kernel_launch(void* const* d_in, const int* in_sizes, int n_in,
                              void* d_out, int out_size, void* d_ws, size_t ws_size,
                              hipStream_t stream)
{
    (void)in_sizes; (void)n_in; (void)out_size; (void)ws_size;
    const float* x1   = (const float*)d_in[0];
    const float* x2   = (const float*)d_in[1];
    const float* PA   = (const float*)d_in[2];
    const float* alp  = (const float*)d_in[3];
    const float* c1w  = (const float*)d_in[4];
    const float* c1b  = (const float*)d_in[5];
    const float* c2w  = (const float*)d_in[6];
    const float* c2b  = (const float*)d_in[7];
    const float* c3w  = (const float*)d_in[8];
    const float* c3b  = (const float*)d_in[9];
    const float* c4w  = (const float*)d_in[10];
    const float* c4b  = (const float*)d_in[11];
    const float* c5w  = (const float*)d_in[12];
    const float* c5b  = (const float*)d_in[13];
    const float* c6w  = (const float*)d_in[14];
    const float* c6b  = (const float*)d_in[15];
    const float* bn1w = (const float*)d_in[16];
    const float* bn1b = (const float*)d_in[17];
    const float* bn2w = (const float*)d_in[18];
    const float* bn2b = (const float*)d_in[19];

    char* ws = (char*)d_ws;
    float*          xmp   = (float*)(ws + 0);                     //    819,200 B
    unsigned short* aw    = (unsigned short*)(ws + 819200);       // 25,165,824 B
    unsigned short* buf0  = (unsigned short*)(ws + 25985024);     // 52,428,800 B
    unsigned short* buf1  = (unsigned short*)(ws + 78413824);     // 52,428,800 B
    // 64-byte poison gap at 130,842,624 (finite-bf16 guard for q=3 overread)
    float*          stats = (float*)(ws + 130842688);             //      1,024 B
    float*          ss    = (float*)(ws + 130843712);             //      1,024 B
    unsigned short* awW   = (unsigned short*)(ws + 130844736);    //    196,608 B
    // total 131,041,344 B

    hipMemsetAsync(stats, 0, 1024, stream);

    k0_means<<<dim3(2, 32, 2), 256, 0, stream>>>(x1, x2, xmp);
    k0b_pack<<<6, 256, 0, stream>>>(c3w, c4w, awW);
    // subsets 0,1 -> buf0,buf1
    kA_conv<<<dim3(100, 32, 2), 256, 0, stream>>>(x1, x2, c3b, c4b, awW,
                                                  buf0, buf1, 0, 2);
    k2_adj<<<192, 256, 0, stream>>>(xmp, PA, alp, c1w, c1b, c2w, c2b,
                                    c5w, c5b, c6w, c6b, aw);
    // z(i0+i1) written over buf0's own rows
    k3bA<<<4096, 256, 0, stream>>>(aw, buf0, buf1);
    // subset 2 -> buf1 (dead after k3bA)
    kA_conv<<<dim3(100, 32, 2), 256, 0, stream>>>(x1, x2, c3b, c4b, awW,
                                                  buf1, buf1, 2, 1);
    // z += i2 contribution (bf16 RMW) + stats
    k3bB<<<4096, 256, 0, stream>>>(aw, buf0, buf1, stats);
    k4_finalize<<<1, 128, 0, stream>>>(stats, bn1w, bn1b, bn2w, bn2b, ss);
    k5_apply<<<25600, 256, 0, stream>>>(x1, x2, buf0, ss, (float*)d_out);
}

// Round 4
// 422.412 us; speedup vs baseline: 1.2489x; 1.2489x over previous
//
#include <hip/hip_runtime.h>

typedef float  f32x4  __attribute__((ext_vector_type(4)));
typedef short  bf16x8 __attribute__((ext_vector_type(8)));
typedef short  s16x4  __attribute__((ext_vector_type(4)));

__device__ __forceinline__ unsigned short f2bf(float f) {
    unsigned int u = __float_as_uint(f);
    unsigned int r = (u + 0x7FFFu + ((u >> 16) & 1u)) >> 16;
    return (unsigned short)r;
}
__device__ __forceinline__ float bf2f(unsigned short h) {
    return __uint_as_float(((unsigned int)h) << 16);
}

// ---------------------------------------------------------------------------
// KT: x (fp32 [c][pos]) -> xT (bf16 [pos][c], channel-last) + t-mean atomics.
// grid (tc=32, n=32, p=2) = 2048 blocks, 256 thr. LDS bf16 tile, stride 225
// (odd => column reads spread across banks).
// ---------------------------------------------------------------------------
__global__ __launch_bounds__(256) void kT_transpose(
    const float* __restrict__ x1, const float* __restrict__ x2,
    float* __restrict__ xm, unsigned short* __restrict__ xT)
{
    const int tc = blockIdx.x, n = blockIdx.y, p = blockIdx.z;
    const float* __restrict__ x = p ? x2 : x1;
    __shared__ unsigned short tile[64 * 225];   // [c][pos 200, stride 225]
    const int tid = threadIdx.x;

    // load phase: 3200 f32x4 (64 c x 50), coalesced; convert; scalar LDS writes
    const size_t xb = (size_t)n * 409600 + (size_t)tc * 200;
    for (int k = 0; k < 13; k++) {
        const int idx = tid + k * 256;
        if (idx < 3200) {
            const int c = idx / 50, l = idx % 50;
            const f32x4 v = *(const f32x4*)(x + xb + (size_t)c * 6400 + l * 4);
            const int base = c * 225 + l * 4;
            tile[base + 0] = f2bf(v[0]);
            tile[base + 1] = f2bf(v[1]);
            tile[base + 2] = f2bf(v[2]);
            tile[base + 3] = f2bf(v[3]);
        }
    }
    __syncthreads();

    // mean partials over this chunk's 8 t's (atomics: 16 adds/address total)
    for (int k = 0; k < 7; k++) {
        const int idx = tid + k * 256;
        if (idx < 1600) {
            const int c = idx / 25, v = idx % 25;
            float s = 0.f;
            #pragma unroll
            for (int t = 0; t < 8; t++) s += bf2f(tile[c * 225 + t * 25 + v]);
            atomicAdd(&xm[((size_t)(p * 32 + n) * 64 + c) * 25 + v],
                      s * (1.0f / 256.0f));
        }
    }

    // store phase: gather 8 channels per lane -> coalesced bf16x8 stores
    for (int k = 0; k < 7; k++) {
        const int idx = tid + k * 256;
        if (idx < 1600) {
            const int c8 = idx & 7, pos = idx >> 3;
            bf16x8 o;
            #pragma unroll
            for (int j = 0; j < 8; j++)
                o[j] = (short)tile[(c8 * 8 + j) * 225 + pos];
            *(bf16x8*)(xT + (((size_t)(p * 32 + n) * 6400 + tc * 200 + pos) * 64
                             + c8 * 8)) = o;
        }
    }
}

// ---------------------------------------------------------------------------
// K0B: pre-pack conv3/conv4 weights into MFMA A-fragment bf16 layout.
// awW: [p*3+i][cg(4)][lane(64)][16 u16]  (af0 | af1)
// ---------------------------------------------------------------------------
__global__ void k0b_pack(const float* __restrict__ c3w, const float* __restrict__ c4w,
                         unsigned short* __restrict__ awW)
{
    const int pi = blockIdx.x;           // p*3+i
    const int p = pi / 3, i = pi % 3;
    const int tid = threadIdx.x;
    const int cg = tid >> 6, lane = tid & 63, q = lane >> 4, m = lane & 15;
    const float* w3 = p ? c4w : c3w;
    const float* wr = w3 + (size_t)(i * 64 + cg * 16 + m) * 64 + q * 8;
    const f32x4 w00 = *(const f32x4*)(wr);
    const f32x4 w01 = *(const f32x4*)(wr + 4);
    const f32x4 w10 = *(const f32x4*)(wr + 32);
    const f32x4 w11 = *(const f32x4*)(wr + 36);
    bf16x8 af0, af1;
    #pragma unroll
    for (int k = 0; k < 4; k++) {
        af0[k] = (short)f2bf(w00[k]); af0[k + 4] = (short)f2bf(w01[k]);
        af1[k] = (short)f2bf(w10[k]); af1[k + 4] = (short)f2bf(w11[k]);
    }
    unsigned short* o = awW + ((size_t)(pi * 4 + cg) * 64 + lane) * 16;
    *(bf16x8*)(o)     = af0;
    *(bf16x8*)(o + 8) = af1;
}

// ---------------------------------------------------------------------------
// K2: r1/r2 -> rel -> a packed as MFMA B-fragments (bf16, zero-padded)
// grid: 192 blocks (i, n, p), 256 threads
// ---------------------------------------------------------------------------
__global__ void k2_adj(const float* __restrict__ xm,
                       const float* __restrict__ PA, const float* __restrict__ alpha,
                       const float* __restrict__ c1w, const float* __restrict__ c1b,
                       const float* __restrict__ c2w, const float* __restrict__ c2b,
                       const float* __restrict__ c5w, const float* __restrict__ c5b,
                       const float* __restrict__ c6w, const float* __restrict__ c6b,
                       unsigned short* __restrict__ aw)
{
    const int b = blockIdx.x;
    const int i = b >> 6;
    const int n = (b >> 1) & 31;
    const int pp = b & 1;
    __shared__ float xml[3200];
    __shared__ float rl[400];
    __shared__ float rel[5000];
    const int tid = threadIdx.x;

    for (int idx = tid; idx < 3200; idx += 256) {
        const int p_ = idx / 1600, rest = idx % 1600;
        xml[idx] = xm[(size_t)(p_ * 32 + n) * 1600 + rest];
    }
    __syncthreads();

    for (int idx = tid; idx < 400; idx += 256) {
        const int which = idx / 200;
        const int rr = (idx % 200) / 25;
        const int v = idx % 25;
        const float* wv = (which ? c2w : c1w) + (i * 8 + rr) * 64;
        const float* xp = xml + which * 1600;
        float s = (which ? c2b : c1b)[i * 8 + rr];
        for (int c = 0; c < 64; c++) s += wv[c] * xp[c * 25 + v];
        rl[idx] = s;
    }
    __syncthreads();

    for (int idx = tid; idx < 5000; idx += 256) {
        const int r_ = idx / 625;
        const int rem = idx - r_ * 625;
        const int u = rem / 25;
        const int v = rem - u * 25;
        rel[idx] = tanhf(rl[r_ * 25 + u] - rl[200 + r_ * 25 + v]);
    }
    __syncthreads();

    const float al = alpha[0];
    {
        const int p_ = pp;
        const float* w5 = p_ ? c6w : c5w;
        const float* b5 = p_ ? c6b : c5b;
        for (int idx = tid; idx < 8192; idx += 256) {
            const int c = idx >> 7;
            const int ut = (idx >> 6) & 1;
            const int lane = idx & 63;
            const int u = ut * 16 + (lane & 15);
            const int qd = lane >> 4;
            bf16x8 outv;
            if (u < 25) {
                float wrow[8];
                #pragma unroll
                for (int r = 0; r < 8; r++) wrow[r] = w5[(i * 64 + c) * 8 + r];
                const float bias = b5[i * 64 + c];
                #pragma unroll
                for (int j = 0; j < 8; j++) {
                    const int v = qd * 8 + j;
                    float s = 0.f;
                    if (v < 25) {
                        s = bias + (p_ ? al : PA[i * 625 + u * 25 + v]);
                        #pragma unroll
                        for (int r = 0; r < 8; r++) s += rel[r * 625 + u * 25 + v] * wrow[r];
                    }
                    outv[j] = (short)f2bf(s);
                }
            } else {
                #pragma unroll
                for (int j = 0; j < 8; j++) outv[j] = 0;
            }
            *(bf16x8*)(aw + ((size_t)((p_ * 3 + i) * 32 + n) * 64 + c) * 1024
                          + ut * 512 + lane * 8) = outv;
        }
    }
}

// ---------------------------------------------------------------------------
// KF: fused conv1x1 (MFMA) + adjacency matmul (MFMA), X3 stays in LDS.
// grid x=(tc 16 | cg 4)=64, y=n 32, z=p 2 => 4096 blocks. 256 thr = 4 waves.
// Block covers: 16 channels (cg), 16 t's (tc), all 3 subsets.
//  stage1: waves split 25 pos-groups; X3 -> shared LDS [cl16][t16][v32].
//  stage2: waves split channels (4 each); acc[4][2] f32x4 = 32 VGPR.
// Epilogue: LDS re-transpose -> coalesced bf16x8 z stores + ppart partials.
// ---------------------------------------------------------------------------
__global__ __launch_bounds__(256, 4) void kF_main(
    const unsigned short* __restrict__ xT,
    const float* __restrict__ c3b, const float* __restrict__ c4b,
    const unsigned short* __restrict__ awW,
    const unsigned short* __restrict__ aw,
    unsigned short* __restrict__ z,
    float* __restrict__ ppart)
{
    const int bx = blockIdx.x;
    const int tc = bx & 15, cg = bx >> 4;
    const int n = blockIdx.y, p = blockIdx.z;
    __shared__ unsigned short X3s[16 * 512];   // [cl][t][v(32, zero-padded)]
    const int tid = threadIdx.x, w = tid >> 6, lane = tid & 63;
    const int q = lane >> 4, m = lane & 15;

    {   // zero once: provides v=25..31 zero padding forever
        int* xi = (int*)X3s;
        #pragma unroll
        for (int k = 0; k < 16; k++) xi[tid + k * 256] = 0;
    }

    const float* __restrict__ b3 = p ? c4b : c3b;
    const size_t xTb = ((size_t)(p * 32 + n) * 6400 + (size_t)tc * 400) * 64;

    f32x4 acc[4][2];
    #pragma unroll
    for (int a = 0; a < 4; a++) {
        acc[a][0] = (f32x4){0.f, 0.f, 0.f, 0.f};
        acc[a][1] = (f32x4){0.f, 0.f, 0.f, 0.f};
    }

    __syncthreads();

    for (int i = 0; i < 3; i++) {
        // ---- stage 1: X3 = W3*x + b for this block's 16 channels ----
        const unsigned short* wp =
            awW + ((size_t)((p * 3 + i) * 4 + cg) * 64 + lane) * 16;
        const bf16x8 af0 = *(const bf16x8*)(wp);
        const bf16x8 af1 = *(const bf16x8*)(wp + 8);
        float bb[4];
        #pragma unroll
        for (int r = 0; r < 4; r++) bb[r] = b3[i * 64 + cg * 16 + q * 4 + r];

        for (int g = w; g < 25; g += 4) {
            const unsigned short* xp = xT + xTb + (size_t)(g * 16 + m) * 64 + q * 8;
            const bf16x8 xb0 = *(const bf16x8*)(xp);
            const bf16x8 xb1 = *(const bf16x8*)(xp + 32);
            f32x4 d = (f32x4){0.f, 0.f, 0.f, 0.f};
            d = __builtin_amdgcn_mfma_f32_16x16x32_bf16(af0, xb0, d, 0, 0, 0);
            d = __builtin_amdgcn_mfma_f32_16x16x32_bf16(af1, xb1, d, 0, 0, 0);
            const int pos = g * 16 + m;
            const int t = pos / 25, v = pos - t * 25;
            #pragma unroll
            for (int r = 0; r < 4; r++)
                X3s[(q * 4 + r) * 512 + t * 32 + v] = f2bf(d[r] + bb[r]);
        }
        __syncthreads();

        // ---- stage 2: Z[c][t][u] += X3[c][t][v] * a[c][u][v] ----
        #pragma unroll
        for (int cl4 = 0; cl4 < 4; cl4++) {
            const int cl = w * 4 + cl4;
            const int c = cg * 16 + cl;
            const bf16x8 A = *(const bf16x8*)(X3s + cl * 512 + m * 32 + q * 8);
            const unsigned short* ab =
                aw + ((size_t)((p * 3 + i) * 32 + n) * 64 + c) * 1024 + lane * 8;
            const bf16x8 B0 = *(const bf16x8*)(ab);
            const bf16x8 B1 = *(const bf16x8*)(ab + 512);
            acc[cl4][0] = __builtin_amdgcn_mfma_f32_16x16x32_bf16(A, B0, acc[cl4][0], 0, 0, 0);
            acc[cl4][1] = __builtin_amdgcn_mfma_f32_16x16x32_bf16(A, B1, acc[cl4][1], 0, 0, 0);
        }
        __syncthreads();
    }

    // ---- epilogue: stats partials + coalesced z store via LDS transpose ----
    #pragma unroll
    for (int cl4 = 0; cl4 < 4; cl4++) {
        float sum = 0.f, ssq = 0.f;
        #pragma unroll
        for (int r = 0; r < 4; r++) {
            const float v0 = acc[cl4][0][r];
            sum += v0; ssq += v0 * v0;
        }
        if (m < 9) {
            #pragma unroll
            for (int r = 0; r < 4; r++) {
                const float v1 = acc[cl4][1][r];
                sum += v1; ssq += v1 * v1;
            }
        }
        #pragma unroll
        for (int off = 32; off > 0; off >>= 1) {
            sum += __shfl_xor(sum, off, 64);
            ssq += __shfl_xor(ssq, off, 64);
        }
        const int c = cg * 16 + w * 4 + cl4;
        if (lane == 0) {
            float* pp = ppart + ((size_t)(p * 64 + c) * 512 + n * 16 + tc) * 2;
            pp[0] = sum; pp[1] = ssq;
        }
        // scatter into wave-private staging (reuse X3s; post-loop barrier done)
        #pragma unroll
        for (int ut = 0; ut < 2; ut++) {
            if (ut == 0 || m < 9) {
                #pragma unroll
                for (int r = 0; r < 4; r++)
                    X3s[w * 1600 + cl4 * 400 + (q * 4 + r) * 25 + ut * 16 + m] =
                        f2bf(acc[cl4][ut][r]);
            }
        }
    }
    // coalesced read-back + 16B global stores (wave-private region: no barrier)
    for (int rd = 0; rd < 4; rd++) {
        const int idx = rd * 64 + lane;
        if (idx < 200) {
            const int cl4 = idx / 50, oct = idx % 50;
            const bf16x8 vz = *(const bf16x8*)(X3s + w * 1600 + cl4 * 400 + oct * 8);
            const int c = cg * 16 + w * 4 + cl4;
            *(bf16x8*)(z + ((size_t)((p * 32 + n) * 64 + c)) * 6400
                         + tc * 400 + oct * 8) = vz;
        }
    }
}

// ---------------------------------------------------------------------------
// K4: reduce ppart (512 partials per (p,c)) -> per-channel scale/shift.
// grid 128 blocks (p*64+c), 64 threads (1 wave).
// ---------------------------------------------------------------------------
__global__ void k4_finalize(const float* __restrict__ ppart,
                            const float* __restrict__ bn1w, const float* __restrict__ bn1b,
                            const float* __restrict__ bn2w, const float* __restrict__ bn2b,
                            float* __restrict__ ss)
{
    const int b = blockIdx.x;            // p*64 + c
    const int t = threadIdx.x;           // 0..63
    const float* base = ppart + (size_t)b * 1024;
    float s = 0.f, qs = 0.f;
    #pragma unroll
    for (int k = 0; k < 8; k++) {
        const int idx = t + 64 * k;
        s  += base[idx * 2];
        qs += base[idx * 2 + 1];
    }
    #pragma unroll
    for (int off = 32; off > 0; off >>= 1) {
        s  += __shfl_xor(s,  off, 64);
        qs += __shfl_xor(qs, off, 64);
    }
    if (t == 0) {
        const int p = b >> 6, c = b & 63;
        const float cnt = 204800.f;      // N*T*V
        const float mean = s / cnt;
        const float var  = qs / cnt - mean * mean;
        const float gw = p ? bn2w[c] : bn1w[c];
        const float gb = p ? bn2b[c] : bn1b[c];
        const float scale = gw * rsqrtf(var + 1e-5f);
        ss[b * 2]     = scale;
        ss[b * 2 + 1] = gb - mean * scale;
    }
}

// ---------------------------------------------------------------------------
// K5: y = relu(z*scale + shift + x), float4-wide
// ---------------------------------------------------------------------------
__global__ void k5_apply(const float* __restrict__ x1, const float* __restrict__ x2,
                         const unsigned short* __restrict__ z, const float* __restrict__ ss,
                         float* __restrict__ out)
{
    const size_t g = (size_t)blockIdx.x * 256 + threadIdx.x;
    const size_t e = g * 4;
    const int p = (int)(e / 13107200u);
    const int c = (int)((e / 6400u) & 63);
    const float* xsrc = p ? x2 : x1;
    const f32x4 xv = *(const f32x4*)(xsrc + (e - (size_t)p * 13107200u));
    const s16x4 zv = *(const s16x4*)(const void*)(z + e);
    const float scale = ss[(p * 64 + c) * 2];
    const float shift = ss[(p * 64 + c) * 2 + 1];
    f32x4 o;
    #pragma unroll
    for (int k = 0; k < 4; k++) {
        const float zf = bf2f((unsigned short)zv[k]);
        const float y = zf * scale + shift + xv[k];
        o[k] = y > 0.f ? y : 0.f;
    }
    *(f32x4*)(out + e) = o;
}

// ---------------------------------------------------------------------------
extern "C" void kernel_launch(void* const* d_in, const int* in_sizes, int n_in,
                              void* d_out, int out_size, void* d_ws, size_t ws_size,
                              hipStream_t stream)
{
    (void)in_sizes; (void)n_in; (void)out_size; (void)ws_size;
    const float* x1   = (const float*)d_in[0];
    const float* x2   = (const float*)d_in[1];
    const float* PA   = (const float*)d_in[2];
    const float* alp  = (const float*)d_in[3];
    const float* c1w  = (const float*)d_in[4];
    const float* c1b  = (const float*)d_in[5];
    const float* c2w  = (const float*)d_in[6];
    const float* c2b  = (const float*)d_in[7];
    const float* c3w  = (const float*)d_in[8];
    const float* c3b  = (const float*)d_in[9];
    const float* c4w  = (const float*)d_in[10];
    const float* c4b  = (const float*)d_in[11];
    const float* c5w  = (const float*)d_in[12];
    const float* c5b  = (const float*)d_in[13];
    const float* c6w  = (const float*)d_in[14];
    const float* c6b  = (const float*)d_in[15];
    const float* bn1w = (const float*)d_in[16];
    const float* bn1b = (const float*)d_in[17];
    const float* bn2w = (const float*)d_in[18];
    const float* bn2b = (const float*)d_in[19];

    char* ws = (char*)d_ws;
    float*          xm    = (float*)(ws + 0);                     //    409,600 B
    unsigned short* aw    = (unsigned short*)(ws + 409600);       // 25,165,824 B
    unsigned short* xT    = (unsigned short*)(ws + 25575424);     // 52,428,800 B
    unsigned short* zbuf  = (unsigned short*)(ws + 78004224);     // 52,428,800 B
    float*          ppart = (float*)(ws + 130433024);             //    524,288 B
    float*          ss    = (float*)(ws + 130957312);             //      1,024 B
    unsigned short* awW   = (unsigned short*)(ws + 130958336);    //     49,152 B
    // total 131,007,488 B <= 131,041,344 proven budget

    hipMemsetAsync(xm, 0, 409600, stream);

    kT_transpose<<<dim3(32, 32, 2), 256, 0, stream>>>(x1, x2, xm, xT);
    k0b_pack<<<6, 256, 0, stream>>>(c3w, c4w, awW);
    k2_adj<<<192, 256, 0, stream>>>(xm, PA, alp, c1w, c1b, c2w, c2b,
                                    c5w, c5b, c6w, c6b, aw);
    kF_main<<<dim3(64, 32, 2), 256, 0, stream>>>(xT, c3b, c4b, awW, aw,
                                                 zbuf, ppart);
    k4_finalize<<<128, 64, 0, stream>>>(ppart, bn1w, bn1b, bn2w, bn2b, ss);
    k5_apply<<<25600, 256, 0, stream>>>(x1, x2, zbuf, ss, (float*)d_out);
}